// Round 2
// baseline (328.135 us; speedup 1.0000x reference)
//
#include <hip/hip_runtime.h>

typedef short bf16x8 __attribute__((ext_vector_type(8)));
typedef float f32x4 __attribute__((ext_vector_type(4)));

#define S_LEN 4096
#define DDIM  64
#define KVB   32
#define NTILES (S_LEN / KVB)

#define MFMA(a, b, c) __builtin_amdgcn_mfma_f32_16x16x32_bf16((a), (b), (c), 0, 0, 0)

// fp32 -> bf16 round-to-nearest-even, returned as bit pattern in short
static __device__ __forceinline__ short f2bf(float f) {
    unsigned u = __builtin_bit_cast(unsigned, f);
    u += 0x7fffu + ((u >> 16) & 1u);
    return (short)(u >> 16);
}
static __device__ __forceinline__ unsigned pk2(float lo, float hi) {
    return (unsigned)(unsigned short)f2bf(lo) |
           ((unsigned)(unsigned short)f2bf(hi) << 16);
}

// A-style fragment read from a row-major [32][64] bf16 LDS tile with
// XOR-swizzle: byte = row*128 + doff*2, byte ^= (row&7)<<4. 16B aligned.
static __device__ __forceinline__ bf16x8 ldfrag(const unsigned char* base, int row, int doff) {
    int addr = (row * 128 + doff * 2) ^ ((row & 7) << 4);
    return *reinterpret_cast<const bf16x8*>(base + addr);
}

__global__ __launch_bounds__(256) void attn_fwd(
    const float* __restrict__ Qg, const float* __restrict__ Kg,
    const float* __restrict__ Vg, float* __restrict__ Og)
{
    const int h    = blockIdx.y;
    const int qb   = blockIdx.x;
    const int tid  = threadIdx.x;
    const int lane = tid & 63;
    const int wv   = tid >> 6;      // wave 0..3, each owns 16 q rows
    const int g    = lane >> 4;     // lane group 0..3
    const int r16  = lane & 15;

    __shared__ __align__(16) unsigned char lds[8192];
    unsigned char* Klds = lds;            // [32][64] bf16, swizzled
    unsigned char* Vlds = lds + 4096;     // [32][64] bf16, swizzled

    // ---- Q fragments: 16 rows per wave, pre-scaled by 1/sqrt(D)=0.125 ----
    const int qrow = qb * 64 + wv * 16 + r16;
    const float* qp = Qg + ((size_t)h * S_LEN + qrow) * DDIM;
    bf16x8 qf[2];
    #pragma unroll
    for (int c = 0; c < 2; ++c) {
        float4 x = *reinterpret_cast<const float4*>(qp + 32 * c + 8 * g);
        float4 y = *reinterpret_cast<const float4*>(qp + 32 * c + 8 * g + 4);
        qf[c][0] = f2bf(x.x * 0.125f); qf[c][1] = f2bf(x.y * 0.125f);
        qf[c][2] = f2bf(x.z * 0.125f); qf[c][3] = f2bf(x.w * 0.125f);
        qf[c][4] = f2bf(y.x * 0.125f); qf[c][5] = f2bf(y.y * 0.125f);
        qf[c][6] = f2bf(y.z * 0.125f); qf[c][7] = f2bf(y.w * 0.125f);
    }

    // ---- identity fragments for the V-transpose MFMA ----
    // B elem (lane,i) must be 1.0 iff (8*g + i) == r16 + 16*ci  (our k-map: 8g+i)
    bf16x8 idf[2];
    #pragma unroll
    for (int c2 = 0; c2 < 2; ++c2) {
        #pragma unroll
        for (int e = 0; e < 8; ++e) {
            bool on = ((g >> 1) == c2) && ((r16 >> 3) == (g & 1)) && (e == (r16 & 7));
            idf[c2][e] = on ? (short)0x3F80 : (short)0;
        }
    }

    // ---- staging assignment: thread t stages row t>>3, d = (t&7)*8 .. +7 ----
    const int    srow   = tid >> 3;
    const int    sd     = (tid & 7) * 8;
    const int    swaddr = (srow * 128 + sd * 2) ^ ((srow & 7) << 4);
    const float* kp = Kg + ((size_t)h * S_LEN + srow) * DDIM + sd;
    const float* vp = Vg + ((size_t)h * S_LEN + srow) * DDIM + sd;

    const f32x4 z0 = {0.f, 0.f, 0.f, 0.f};
    f32x4 acc[4] = {z0, z0, z0, z0};     // O^T accum: acc[dk] -> d = 16*dk + 4*g + j, q = r16
    float mrun = -INFINITY, lrun = 0.f;

    for (int kt = 0; kt < NTILES; ++kt) {
        // ---- stage K,V tile (fp32 -> bf16 -> LDS, swizzled b128 writes) ----
        {
            float4 a = *reinterpret_cast<const float4*>(kp);
            float4 b = *reinterpret_cast<const float4*>(kp + 4);
            int4 wk;
            wk.x = (int)pk2(a.x, a.y); wk.y = (int)pk2(a.z, a.w);
            wk.z = (int)pk2(b.x, b.y); wk.w = (int)pk2(b.z, b.w);
            *reinterpret_cast<int4*>(Klds + swaddr) = wk;

            float4 c = *reinterpret_cast<const float4*>(vp);
            float4 d = *reinterpret_cast<const float4*>(vp + 4);
            int4 wvv;
            wvv.x = (int)pk2(c.x, c.y); wvv.y = (int)pk2(c.z, c.w);
            wvv.z = (int)pk2(d.x, d.y); wvv.w = (int)pk2(d.z, d.w);
            *reinterpret_cast<int4*>(Vlds + swaddr) = wvv;

            kp += KVB * DDIM; vp += KVB * DDIM;
        }
        __syncthreads();

        // ---- QK^T (swapped): s0/s1 = S^T C/D tiles, keys 4g+j (+16), q = r16 ----
        f32x4 s0 = z0, s1 = z0;
        #pragma unroll
        for (int c = 0; c < 2; ++c) {
            bf16x8 k0 = ldfrag(Klds, r16,      32 * c + 8 * g);
            bf16x8 k1 = ldfrag(Klds, 16 + r16, 32 * c + 8 * g);
            s0 = MFMA(k0, qf[c], s0);
            s1 = MFMA(k1, qf[c], s1);
        }

        // ---- online softmax (per q = r16; 4 lanes share a q row) ----
        float pm = s0[0];
        pm = fmaxf(pm, s0[1]); pm = fmaxf(pm, s0[2]); pm = fmaxf(pm, s0[3]);
        pm = fmaxf(pm, s1[0]); pm = fmaxf(pm, s1[1]);
        pm = fmaxf(pm, s1[2]); pm = fmaxf(pm, s1[3]);
        pm = fmaxf(pm, __shfl_xor(pm, 16));
        pm = fmaxf(pm, __shfl_xor(pm, 32));
        float mnew  = fmaxf(mrun, pm);
        float alpha = __expf(mrun - mnew);
        float p0[4], p1[4];
        float ls = 0.f;
        #pragma unroll
        for (int j = 0; j < 4; ++j) {
            p0[j] = __expf(s0[j] - mnew);
            p1[j] = __expf(s1[j] - mnew);
            ls += p0[j] + p1[j];
        }
        ls += __shfl_xor(ls, 16);
        ls += __shfl_xor(ls, 32);
        lrun = lrun * alpha + ls;
        mrun = mnew;
        #pragma unroll
        for (int dk = 0; dk < 4; ++dk) {
            #pragma unroll
            for (int j = 0; j < 4; ++j) acc[dk][j] *= alpha;
        }

        // ---- P -> bf16 B-operand (same k-map as V^T A-operand below) ----
        bf16x8 pb;
        pb[0] = f2bf(p0[0]); pb[1] = f2bf(p0[1]); pb[2] = f2bf(p0[2]); pb[3] = f2bf(p0[3]);
        pb[4] = f2bf(p1[0]); pb[5] = f2bf(p1[1]); pb[6] = f2bf(p1[2]); pb[7] = f2bf(p1[3]);

        // ---- V^T via identity-MFMA (exact: bf16 * 1.0 in fp32) ----
        f32x4 vt[2][4];
        #pragma unroll
        for (int s2 = 0; s2 < 2; ++s2) {
            #pragma unroll
            for (int dc = 0; dc < 2; ++dc) {
                bf16x8 av = ldfrag(Vlds, 16 * s2 + r16, 32 * dc + 8 * g);
                vt[s2][2 * dc + 0] = MFMA(av, idf[0], z0);
                vt[s2][2 * dc + 1] = MFMA(av, idf[1], z0);
            }
        }

        // ---- PV: acc[dk] += V^T_chunk * P^T ----
        #pragma unroll
        for (int dk = 0; dk < 4; ++dk) {
            bf16x8 vf;
            vf[0] = f2bf(vt[0][dk][0]); vf[1] = f2bf(vt[0][dk][1]);
            vf[2] = f2bf(vt[0][dk][2]); vf[3] = f2bf(vt[0][dk][3]);
            vf[4] = f2bf(vt[1][dk][0]); vf[5] = f2bf(vt[1][dk][1]);
            vf[6] = f2bf(vt[1][dk][2]); vf[7] = f2bf(vt[1][dk][3]);
            acc[dk] = MFMA(vf, pb, acc[dk]);
        }

        __syncthreads();
    }

    // ---- epilogue: O = O^T_acc / l, vectorized 16B stores ----
    float inv = 1.0f / lrun;
    float* op = Og + ((size_t)h * S_LEN + qrow) * DDIM;
    #pragma unroll
    for (int dk = 0; dk < 4; ++dk) {
        float4 o;
        o.x = acc[dk][0] * inv; o.y = acc[dk][1] * inv;
        o.z = acc[dk][2] * inv; o.w = acc[dk][3] * inv;
        *reinterpret_cast<float4*>(op + 16 * dk + 4 * g) = o;
    }
}

extern "C" void kernel_launch(void* const* d_in, const int* in_sizes, int n_in,
                              void* d_out, int out_size, void* d_ws, size_t ws_size,
                              hipStream_t stream) {
    const float* Q = (const float*)d_in[0];
    const float* K = (const float*)d_in[1];
    const float* V = (const float*)d_in[2];
    float* O = (float*)d_out;
    dim3 grid(S_LEN / 64, 16, 1);
    attn_fwd<<<grid, dim3(256, 1, 1), 0, stream>>>(Q, K, V, O);
}

// Round 4
// 192.669 us; speedup vs baseline: 1.7031x; 1.7031x over previous
//
#include <hip/hip_runtime.h>
#include <hip/hip_bf16.h>

typedef short bf16x8 __attribute__((ext_vector_type(8)));
typedef float f32x4 __attribute__((ext_vector_type(4)));

#define S_LEN 4096
#define DDIM  64
#define KVB   32
#define NTILES (S_LEN / KVB)
#define QBLK  128               // q rows per block (4 waves x 32)
#define THR   7.0f              // defer-max threshold (log2 domain): P <= 2^7

#define MFMA(a, b, c) __builtin_amdgcn_mfma_f32_16x16x32_bf16((a), (b), (c), 0, 0, 0)

// base-2 exp via v_exp_f32 (avoid __exp2f: glibc macro collision)
static __device__ __forceinline__ float exp2v(float x) {
    return __builtin_amdgcn_exp2f(x);
}

// fp32 -> bf16 RNE via HW conversion (compiler emits cvt)
static __device__ __forceinline__ short f2bf(float f) {
    return __builtin_bit_cast(short, __float2bfloat16(f));
}
static __device__ __forceinline__ unsigned pk2rne(float lo, float hi) {
    unsigned a = (unsigned)(unsigned short)f2bf(lo);
    unsigned b = (unsigned)(unsigned short)f2bf(hi);
    return a | (b << 16);
}
// exact truncation pack: both floats carry exact bf16 values -> take top16
static __device__ __forceinline__ unsigned pk2t(float lo, float hi) {
    return __builtin_amdgcn_perm(__builtin_bit_cast(unsigned, hi),
                                 __builtin_bit_cast(unsigned, lo), 0x07060302u);
}

// fragment read from row-major [32][64] bf16 LDS tile, XOR-swizzled
static __device__ __forceinline__ bf16x8 ldfrag(const unsigned char* base, int row, int doff) {
    int addr = (row * 128 + doff * 2) ^ ((row & 7) << 4);
    return *reinterpret_cast<const bf16x8*>(base + addr);
}

// stage one K/V 32x64 tile (fp32 regs -> bf16 -> swizzled LDS b128 writes)
static __device__ __forceinline__ void stage(unsigned char* base, int swaddr,
                                             float4 a, float4 b, float4 c, float4 d) {
    int4 wk;
    wk.x = (int)pk2rne(a.x, a.y); wk.y = (int)pk2rne(a.z, a.w);
    wk.z = (int)pk2rne(b.x, b.y); wk.w = (int)pk2rne(b.z, b.w);
    *reinterpret_cast<int4*>(base + swaddr) = wk;
    int4 wv;
    wv.x = (int)pk2rne(c.x, c.y); wv.y = (int)pk2rne(c.z, c.w);
    wv.z = (int)pk2rne(d.x, d.y); wv.w = (int)pk2rne(d.z, d.w);
    *reinterpret_cast<int4*>(base + 4096 + swaddr) = wv;
}

__global__ __launch_bounds__(256) void attn_fwd(
    const float* __restrict__ Qg, const float* __restrict__ Kg,
    const float* __restrict__ Vg, float* __restrict__ Og)
{
    const int h    = blockIdx.y;
    const int qb   = blockIdx.x;
    const int tid  = threadIdx.x;
    const int lane = tid & 63;
    const int wv   = tid >> 6;      // wave 0..3, each owns 32 q rows
    const int g    = lane >> 4;     // lane group 0..3
    const int r16  = lane & 15;

    __shared__ __align__(16) unsigned char lds[16384];   // 2 bufs x (K 4K + V 4K)

    // ---- Q fragments: 2 sets of 16 rows, pre-scaled by log2(e)/sqrt(D) ----
    const float QSC = 0.125f * 1.44269504088896f;
    const int qrow0 = qb * QBLK + wv * 32 + r16;
    bf16x8 qf0[2], qf1[2];
    {
        const float* qp0 = Qg + ((size_t)h * S_LEN + qrow0) * DDIM;
        const float* qp1 = qp0 + 16 * DDIM;
        #pragma unroll
        for (int c = 0; c < 2; ++c) {
            float4 x = *reinterpret_cast<const float4*>(qp0 + 32 * c + 8 * g);
            float4 y = *reinterpret_cast<const float4*>(qp0 + 32 * c + 8 * g + 4);
            int4 w;
            w.x = (int)pk2rne(x.x * QSC, x.y * QSC); w.y = (int)pk2rne(x.z * QSC, x.w * QSC);
            w.z = (int)pk2rne(y.x * QSC, y.y * QSC); w.w = (int)pk2rne(y.z * QSC, y.w * QSC);
            qf0[c] = __builtin_bit_cast(bf16x8, w);
            x = *reinterpret_cast<const float4*>(qp1 + 32 * c + 8 * g);
            y = *reinterpret_cast<const float4*>(qp1 + 32 * c + 8 * g + 4);
            w.x = (int)pk2rne(x.x * QSC, x.y * QSC); w.y = (int)pk2rne(x.z * QSC, x.w * QSC);
            w.z = (int)pk2rne(y.x * QSC, y.y * QSC); w.w = (int)pk2rne(y.z * QSC, y.w * QSC);
            qf1[c] = __builtin_bit_cast(bf16x8, w);
        }
    }

    // ---- identity fragments for the V-transpose MFMA (same k-map: 8g+e) ----
    bf16x8 idf[2];
    #pragma unroll
    for (int c2 = 0; c2 < 2; ++c2) {
        #pragma unroll
        for (int e = 0; e < 8; ++e) {
            bool on = ((g >> 1) == c2) && ((r16 >> 3) == (g & 1)) && (e == (r16 & 7));
            idf[c2][e] = on ? (short)0x3F80 : (short)0;
        }
    }

    // ---- staging assignment ----
    const int srow   = tid >> 3;
    const int sd     = (tid & 7) * 8;
    const int swaddr = (srow * 128 + sd * 2) ^ ((srow & 7) << 4);
    const size_t hoff = (size_t)h * S_LEN * DDIM;
    const float* kp = Kg + hoff + (size_t)srow * DDIM + sd;
    const float* vp = Vg + hoff + (size_t)srow * DDIM + sd;

    // prologue: tile 0 -> buf0; tile 1 -> regs
    float4 ka = *reinterpret_cast<const float4*>(kp);
    float4 kb = *reinterpret_cast<const float4*>(kp + 4);
    float4 va = *reinterpret_cast<const float4*>(vp);
    float4 vb = *reinterpret_cast<const float4*>(vp + 4);
    stage(lds, swaddr, ka, kb, va, vb);
    kp += KVB * DDIM; vp += KVB * DDIM;
    ka = *reinterpret_cast<const float4*>(kp);
    kb = *reinterpret_cast<const float4*>(kp + 4);
    va = *reinterpret_cast<const float4*>(vp);
    vb = *reinterpret_cast<const float4*>(vp + 4);
    __syncthreads();

    const f32x4 z0 = {0.f, 0.f, 0.f, 0.f};
    f32x4 accA[4] = {z0, z0, z0, z0};    // set0: d = 16dk+4g+j, q = r16
    f32x4 accB[4] = {z0, z0, z0, z0};    // set1: q = 16 + r16
    float m0 = -INFINITY, l0 = 0.f, m1 = -INFINITY, l1 = 0.f;

    int c = 0;
    for (int kt = 0; kt < NTILES; ++kt) {
        const unsigned char* Klds = lds + c * 8192;
        const unsigned char* Vlds = lds + c * 8192 + 4096;

        // write next tile into other buffer; issue loads for tile kt+2
        if (kt + 1 < NTILES) {
            stage(lds + (c ^ 1) * 8192, swaddr, ka, kb, va, vb);
            if (kt + 2 < NTILES) {
                kp += KVB * DDIM; vp += KVB * DDIM;
                ka = *reinterpret_cast<const float4*>(kp);
                kb = *reinterpret_cast<const float4*>(kp + 4);
                va = *reinterpret_cast<const float4*>(vp);
                vb = *reinterpret_cast<const float4*>(vp + 4);
            }
        }

        // ---- QK^T (swapped): S^T tiles; keys 4g+j (+16), q = r16 (sets share K) ----
        f32x4 sA0 = z0, sA1 = z0, sB0 = z0, sB1 = z0;
        #pragma unroll
        for (int cc = 0; cc < 2; ++cc) {
            bf16x8 k0 = ldfrag(Klds, r16,      32 * cc + 8 * g);
            bf16x8 k1 = ldfrag(Klds, 16 + r16, 32 * cc + 8 * g);
            sA0 = MFMA(k0, qf0[cc], sA0);
            sA1 = MFMA(k1, qf0[cc], sA1);
            sB0 = MFMA(k0, qf1[cc], sB0);
            sB1 = MFMA(k1, qf1[cc], sB1);
        }

        // ---- V^T via identity-MFMA, shared by both q-sets ----
        f32x4 vt[2][4];
        #pragma unroll
        for (int s2 = 0; s2 < 2; ++s2) {
            #pragma unroll
            for (int dc = 0; dc < 2; ++dc) {
                bf16x8 av = ldfrag(Vlds, 16 * s2 + r16, 32 * dc + 8 * g);
                vt[s2][2 * dc + 0] = MFMA(av, idf[0], z0);
                vt[s2][2 * dc + 1] = MFMA(av, idf[1], z0);
            }
        }
        bf16x8 vf[4];
        #pragma unroll
        for (int dk = 0; dk < 4; ++dk) {
            int4 w;
            w.x = (int)pk2t(vt[0][dk][0], vt[0][dk][1]);
            w.y = (int)pk2t(vt[0][dk][2], vt[0][dk][3]);
            w.z = (int)pk2t(vt[1][dk][0], vt[1][dk][1]);
            w.w = (int)pk2t(vt[1][dk][2], vt[1][dk][3]);
            vf[dk] = __builtin_bit_cast(bf16x8, w);
        }

        // ---- online softmax, set 0 (base-2 domain) ----
        {
            float pm = fmaxf(fmaxf(fmaxf(sA0[0], sA0[1]), fmaxf(sA0[2], sA0[3])),
                             fmaxf(fmaxf(sA1[0], sA1[1]), fmaxf(sA1[2], sA1[3])));
            pm = fmaxf(pm, __shfl_xor(pm, 16));
            pm = fmaxf(pm, __shfl_xor(pm, 32));
            if (!__all(pm <= m0 + THR)) {
                float mn = fmaxf(m0, pm);
                float al = exp2v(m0 - mn);
                l0 *= al;
                #pragma unroll
                for (int dk = 0; dk < 4; ++dk)
                    #pragma unroll
                    for (int j = 0; j < 4; ++j) accA[dk][j] *= al;
                m0 = mn;
            }
            float p[8], ls = 0.f;
            #pragma unroll
            for (int j = 0; j < 4; ++j) { p[j] = exp2v(sA0[j] - m0); ls += p[j]; }
            #pragma unroll
            for (int j = 0; j < 4; ++j) { p[4 + j] = exp2v(sA1[j] - m0); ls += p[4 + j]; }
            ls += __shfl_xor(ls, 16);
            ls += __shfl_xor(ls, 32);
            l0 += ls;
            int4 w;
            w.x = (int)pk2rne(p[0], p[1]); w.y = (int)pk2rne(p[2], p[3]);
            w.z = (int)pk2rne(p[4], p[5]); w.w = (int)pk2rne(p[6], p[7]);
            bf16x8 pb = __builtin_bit_cast(bf16x8, w);
            #pragma unroll
            for (int dk = 0; dk < 4; ++dk) accA[dk] = MFMA(vf[dk], pb, accA[dk]);
        }

        // ---- online softmax, set 1 ----
        {
            float pm = fmaxf(fmaxf(fmaxf(sB0[0], sB0[1]), fmaxf(sB0[2], sB0[3])),
                             fmaxf(fmaxf(sB1[0], sB1[1]), fmaxf(sB1[2], sB1[3])));
            pm = fmaxf(pm, __shfl_xor(pm, 16));
            pm = fmaxf(pm, __shfl_xor(pm, 32));
            if (!__all(pm <= m1 + THR)) {
                float mn = fmaxf(m1, pm);
                float al = exp2v(m1 - mn);
                l1 *= al;
                #pragma unroll
                for (int dk = 0; dk < 4; ++dk)
                    #pragma unroll
                    for (int j = 0; j < 4; ++j) accB[dk][j] *= al;
                m1 = mn;
            }
            float p[8], ls = 0.f;
            #pragma unroll
            for (int j = 0; j < 4; ++j) { p[j] = exp2v(sB0[j] - m1); ls += p[j]; }
            #pragma unroll
            for (int j = 0; j < 4; ++j) { p[4 + j] = exp2v(sB1[j] - m1); ls += p[4 + j]; }
            ls += __shfl_xor(ls, 16);
            ls += __shfl_xor(ls, 32);
            l1 += ls;
            int4 w;
            w.x = (int)pk2rne(p[0], p[1]); w.y = (int)pk2rne(p[2], p[3]);
            w.z = (int)pk2rne(p[4], p[5]); w.w = (int)pk2rne(p[6], p[7]);
            bf16x8 pb = __builtin_bit_cast(bf16x8, w);
            #pragma unroll
            for (int dk = 0; dk < 4; ++dk) accB[dk] = MFMA(vf[dk], pb, accB[dk]);
        }

        __syncthreads();
        c ^= 1;
    }

    // ---- epilogue ----
    {
        float inv = 1.0f / l0;
        float* op = Og + ((size_t)h * S_LEN + qrow0) * DDIM;
        #pragma unroll
        for (int dk = 0; dk < 4; ++dk) {
            float4 o;
            o.x = accA[dk][0] * inv; o.y = accA[dk][1] * inv;
            o.z = accA[dk][2] * inv; o.w = accA[dk][3] * inv;
            *reinterpret_cast<float4*>(op + 16 * dk + 4 * g) = o;
        }
    }
    {
        float inv = 1.0f / l1;
        float* op = Og + ((size_t)h * S_LEN + qrow0 + 16) * DDIM;
        #pragma unroll
        for (int dk = 0; dk < 4; ++dk) {
            float4 o;
            o.x = accB[dk][0] * inv; o.y = accB[dk][1] * inv;
            o.z = accB[dk][2] * inv; o.w = accB[dk][3] * inv;
            *reinterpret_cast<float4*>(op + 16 * dk + 4 * g) = o;
        }
    }
}

extern "C" void kernel_launch(void* const* d_in, const int* in_sizes, int n_in,
                              void* d_out, int out_size, void* d_ws, size_t ws_size,
                              hipStream_t stream) {
    const float* Q = (const float*)d_in[0];
    const float* K = (const float*)d_in[1];
    const float* V = (const float*)d_in[2];
    float* O = (float*)d_out;
    dim3 grid(S_LEN / QBLK, 16, 1);
    attn_fwd<<<grid, dim3(256, 1, 1), 0, stream>>>(Q, K, V, O);
}

// Round 5
// 178.646 us; speedup vs baseline: 1.8368x; 1.0785x over previous
//
#include <hip/hip_runtime.h>
#include <hip/hip_bf16.h>

typedef short bf16x8 __attribute__((ext_vector_type(8)));
typedef __bf16 bfv8  __attribute__((ext_vector_type(8)));
typedef float f32x4  __attribute__((ext_vector_type(4)));

#define S_LEN 4096
#define DDIM  64
#define KVB   32
#define QBLK  128               // q rows per block (4 waves x 32)
#define NHEAD 16
#define THR   7.0f              // defer-max threshold (log2 domain)

#define MFMA(a, b, c) __builtin_amdgcn_mfma_f32_16x16x32_bf16((a), (b), (c), 0, 0, 0)

// base-2 exp via v_exp_f32 (avoid __exp2f: glibc macro collision)
static __device__ __forceinline__ float exp2v(float x) {
    return __builtin_amdgcn_exp2f(x);
}

// exact truncation pack: both floats carry exact bf16 values -> take top16
static __device__ __forceinline__ unsigned pk2t(float lo, float hi) {
    return __builtin_amdgcn_perm(__builtin_bit_cast(unsigned, hi),
                                 __builtin_bit_cast(unsigned, lo), 0x07060302u);
}

// 8x fp32 -> bf16 RNE via native __bf16 casts (compiler fuses to v_cvt_pk_bf16_f32)
static __device__ __forceinline__ int4 cvt8(float4 a, float4 b) {
    bfv8 r;
    r[0] = (__bf16)a.x; r[1] = (__bf16)a.y; r[2] = (__bf16)a.z; r[3] = (__bf16)a.w;
    r[4] = (__bf16)b.x; r[5] = (__bf16)b.y; r[6] = (__bf16)b.z; r[7] = (__bf16)b.w;
    return __builtin_bit_cast(int4, r);
}

// fragment read from row-major [32][64] bf16 LDS tile, XOR-swizzled
static __device__ __forceinline__ bf16x8 ldfrag(const unsigned char* base, int row, int doff) {
    int addr = (row * 128 + doff * 2) ^ ((row & 7) << 4);
    return *reinterpret_cast<const bf16x8*>(base + addr);
}

// stage one K/V 32x64 tile pair (fp32 regs -> bf16 -> swizzled LDS b128 writes)
static __device__ __forceinline__ void stage(unsigned char* base, int swaddr,
                                             float4 a, float4 b, float4 c, float4 d) {
    *reinterpret_cast<int4*>(base + swaddr)        = cvt8(a, b);
    *reinterpret_cast<int4*>(base + 4096 + swaddr) = cvt8(c, d);
}

// online softmax + PV accumulate for one 16-row q-set (base-2 domain)
static __device__ __forceinline__ void sm_pv(f32x4 s0, f32x4 s1, float& m, float& l,
                                             f32x4 acc[4], const bf16x8 vf[4]) {
    // max3-friendly chain
    float pm = fmaxf(fmaxf(s0[0], s0[1]), s0[2]);
    pm = fmaxf(fmaxf(pm, s0[3]), s1[0]);
    pm = fmaxf(fmaxf(pm, s1[1]), s1[2]);
    pm = fmaxf(pm, s1[3]);
    pm = fmaxf(pm, __shfl_xor(pm, 16));
    pm = fmaxf(pm, __shfl_xor(pm, 32));
    if (!__all(pm <= m + THR)) {        // defer-max: skip rescale on small growth
        float mn = fmaxf(m, pm);
        float al = exp2v(m - mn);
        l *= al;
        #pragma unroll
        for (int dk = 0; dk < 4; ++dk)
            #pragma unroll
            for (int j = 0; j < 4; ++j) acc[dk][j] *= al;
        m = mn;
    }
    float p[8], ls = 0.f;
    #pragma unroll
    for (int j = 0; j < 4; ++j) { p[j]     = exp2v(s0[j] - m); ls += p[j]; }
    #pragma unroll
    for (int j = 0; j < 4; ++j) { p[4 + j] = exp2v(s1[j] - m); ls += p[4 + j]; }
    ls += __shfl_xor(ls, 16);
    ls += __shfl_xor(ls, 32);
    l += ls;
    bfv8 r;
    #pragma unroll
    for (int j = 0; j < 8; ++j) r[j] = (__bf16)p[j];
    bf16x8 pb = __builtin_bit_cast(bf16x8, r);
    #pragma unroll
    for (int dk = 0; dk < 4; ++dk) acc[dk] = MFMA(vf[dk], pb, acc[dk]);
}

template <int KSPLIT>
__global__ __launch_bounds__(256) void attn_fwd(
    const float* __restrict__ Qg, const float* __restrict__ Kg,
    const float* __restrict__ Vg, float* __restrict__ Og,
    float* __restrict__ wsO, float* __restrict__ wsML)
{
    const int h    = blockIdx.y;
    const int qb   = blockIdx.x;
    const int ks   = (KSPLIT > 1) ? blockIdx.z : 0;
    const int NT   = (S_LEN / KVB) / KSPLIT;
    const int tid  = threadIdx.x;
    const int lane = tid & 63;
    const int wv   = tid >> 6;      // wave 0..3, each owns 32 q rows
    const int g    = lane >> 4;     // lane group 0..3
    const int r16  = lane & 15;

    __shared__ __align__(16) unsigned char lds[16384];   // 2 bufs x (K 4K + V 4K)

    // ---- Q fragments: 2 sets of 16 rows, pre-scaled by log2(e)/sqrt(D) ----
    const float QSC = 0.125f * 1.44269504088896f;
    const int qrow0 = qb * QBLK + wv * 32 + r16;
    bf16x8 qf0[2], qf1[2];
    {
        const float* qp0 = Qg + ((size_t)h * S_LEN + qrow0) * DDIM;
        const float* qp1 = qp0 + 16 * DDIM;
        #pragma unroll
        for (int c = 0; c < 2; ++c) {
            float4 x = *reinterpret_cast<const float4*>(qp0 + 32 * c + 8 * g);
            float4 y = *reinterpret_cast<const float4*>(qp0 + 32 * c + 8 * g + 4);
            float4 xs = {x.x * QSC, x.y * QSC, x.z * QSC, x.w * QSC};
            float4 ys = {y.x * QSC, y.y * QSC, y.z * QSC, y.w * QSC};
            qf0[c] = __builtin_bit_cast(bf16x8, cvt8(xs, ys));
            x = *reinterpret_cast<const float4*>(qp1 + 32 * c + 8 * g);
            y = *reinterpret_cast<const float4*>(qp1 + 32 * c + 8 * g + 4);
            xs = {x.x * QSC, x.y * QSC, x.z * QSC, x.w * QSC};
            ys = {y.x * QSC, y.y * QSC, y.z * QSC, y.w * QSC};
            qf1[c] = __builtin_bit_cast(bf16x8, cvt8(xs, ys));
        }
    }

    // ---- identity fragments for the V-transpose MFMA (k-map: 8g+e) ----
    bf16x8 idf[2];
    #pragma unroll
    for (int c2 = 0; c2 < 2; ++c2) {
        #pragma unroll
        for (int e = 0; e < 8; ++e) {
            bool on = ((g >> 1) == c2) && ((r16 >> 3) == (g & 1)) && (e == (r16 & 7));
            idf[c2][e] = on ? (short)0x3F80 : (short)0;
        }
    }

    // ---- staging assignment ----
    const int srow   = tid >> 3;
    const int sd     = (tid & 7) * 8;
    const int swaddr = (srow * 128 + sd * 2) ^ ((srow & 7) << 4);
    const size_t kvoff = (size_t)h * S_LEN * DDIM
                       + (size_t)ks * (S_LEN / KSPLIT) * DDIM
                       + (size_t)srow * DDIM + sd;
    const float* kp = Kg + kvoff;
    const float* vp = Vg + kvoff;

    // prologue: tile 0 -> buf0; tile 1 -> regs
    float4 ka = *reinterpret_cast<const float4*>(kp);
    float4 kb = *reinterpret_cast<const float4*>(kp + 4);
    float4 va = *reinterpret_cast<const float4*>(vp);
    float4 vb = *reinterpret_cast<const float4*>(vp + 4);
    stage(lds, swaddr, ka, kb, va, vb);
    kp += KVB * DDIM; vp += KVB * DDIM;
    ka = *reinterpret_cast<const float4*>(kp);
    kb = *reinterpret_cast<const float4*>(kp + 4);
    va = *reinterpret_cast<const float4*>(vp);
    vb = *reinterpret_cast<const float4*>(vp + 4);
    __syncthreads();

    const f32x4 z0 = {0.f, 0.f, 0.f, 0.f};
    f32x4 accA[4] = {z0, z0, z0, z0};    // set0: d = 16dk+4g+j, q = r16
    f32x4 accB[4] = {z0, z0, z0, z0};    // set1: q = 16 + r16
    float m0 = -INFINITY, l0 = 0.f, m1 = -INFINITY, l1 = 0.f;

    int c = 0;
    for (int kt = 0; kt < NT; ++kt) {
        const unsigned char* Klds = lds + c * 8192;
        const unsigned char* Vlds = lds + c * 8192 + 4096;

        // write next tile into other buffer; issue loads for tile kt+2
        if (kt + 1 < NT) {
            stage(lds + (c ^ 1) * 8192, swaddr, ka, kb, va, vb);
            if (kt + 2 < NT) {
                kp += KVB * DDIM; vp += KVB * DDIM;
                ka = *reinterpret_cast<const float4*>(kp);
                kb = *reinterpret_cast<const float4*>(kp + 4);
                va = *reinterpret_cast<const float4*>(vp);
                vb = *reinterpret_cast<const float4*>(vp + 4);
            }
        }

        // ---- QK^T (swapped): S^T tiles; keys 4g+j (+16), q = r16 ----
        f32x4 sA0 = z0, sA1 = z0, sB0 = z0, sB1 = z0;
        #pragma unroll
        for (int cc = 0; cc < 2; ++cc) {
            bf16x8 k0 = ldfrag(Klds, r16,      32 * cc + 8 * g);
            bf16x8 k1 = ldfrag(Klds, 16 + r16, 32 * cc + 8 * g);
            sA0 = MFMA(k0, qf0[cc], sA0);
            sA1 = MFMA(k1, qf0[cc], sA1);
            sB0 = MFMA(k0, qf1[cc], sB0);
            sB1 = MFMA(k1, qf1[cc], sB1);
        }

        // ---- V^T via identity-MFMA, shared by both q-sets ----
        f32x4 vt[2][4];
        #pragma unroll
        for (int s2 = 0; s2 < 2; ++s2) {
            #pragma unroll
            for (int dc = 0; dc < 2; ++dc) {
                bf16x8 av = ldfrag(Vlds, 16 * s2 + r16, 32 * dc + 8 * g);
                vt[s2][2 * dc + 0] = MFMA(av, idf[0], z0);
                vt[s2][2 * dc + 1] = MFMA(av, idf[1], z0);
            }
        }
        bf16x8 vf[4];
        #pragma unroll
        for (int dk = 0; dk < 4; ++dk) {
            int4 w;
            w.x = (int)pk2t(vt[0][dk][0], vt[0][dk][1]);
            w.y = (int)pk2t(vt[0][dk][2], vt[0][dk][3]);
            w.z = (int)pk2t(vt[1][dk][0], vt[1][dk][1]);
            w.w = (int)pk2t(vt[1][dk][2], vt[1][dk][3]);
            vf[dk] = __builtin_bit_cast(bf16x8, w);
        }

        sm_pv(sA0, sA1, m0, l0, accA, vf);
        sm_pv(sB0, sB1, m1, l1, accB, vf);

        __syncthreads();
        c ^= 1;
    }

    // ---- epilogue ----
    if (KSPLIT == 1) {
        float inv0 = 1.0f / l0;
        float* op = Og + ((size_t)h * S_LEN + qrow0) * DDIM;
        #pragma unroll
        for (int dk = 0; dk < 4; ++dk) {
            float4 o = {accA[dk][0] * inv0, accA[dk][1] * inv0,
                        accA[dk][2] * inv0, accA[dk][3] * inv0};
            *reinterpret_cast<float4*>(op + 16 * dk + 4 * g) = o;
        }
        float inv1 = 1.0f / l1;
        op += 16 * DDIM;
        #pragma unroll
        for (int dk = 0; dk < 4; ++dk) {
            float4 o = {accB[dk][0] * inv1, accB[dk][1] * inv1,
                        accB[dk][2] * inv1, accB[dk][3] * inv1};
            *reinterpret_cast<float4*>(op + 16 * dk + 4 * g) = o;
        }
    } else {
        // unnormalized partials + (m, l) per row
        const size_t R0 = (size_t)h * S_LEN + qrow0;
        float* o0 = wsO + ((size_t)ks * (NHEAD * S_LEN) + R0) * DDIM;
        #pragma unroll
        for (int dk = 0; dk < 4; ++dk) {
            float4 o = {accA[dk][0], accA[dk][1], accA[dk][2], accA[dk][3]};
            *reinterpret_cast<float4*>(o0 + 16 * dk + 4 * g) = o;
        }
        o0 += 16 * DDIM;
        #pragma unroll
        for (int dk = 0; dk < 4; ++dk) {
            float4 o = {accB[dk][0], accB[dk][1], accB[dk][2], accB[dk][3]};
            *reinterpret_cast<float4*>(o0 + 16 * dk + 4 * g) = o;
        }
        if (g == 0) {
            float2 v0 = {m0, l0};
            float2 v1 = {m1, l1};
            *reinterpret_cast<float2*>(wsML + ((size_t)ks * (NHEAD * S_LEN) + R0) * 2)      = v0;
            *reinterpret_cast<float2*>(wsML + ((size_t)ks * (NHEAD * S_LEN) + R0 + 16) * 2) = v1;
        }
    }
}

__global__ __launch_bounds__(256) void combine2(
    const float* __restrict__ wsO, const float* __restrict__ wsML,
    float* __restrict__ Og)
{
    const int NR = NHEAD * S_LEN;
    int t  = blockIdx.x * 256 + threadIdx.x;     // one float4 of O per thread
    int R  = t >> 4;
    int d4 = (t & 15) * 4;
    float2 ml0 = *reinterpret_cast<const float2*>(wsML + (size_t)R * 2);
    float2 ml1 = *reinterpret_cast<const float2*>(wsML + ((size_t)NR + R) * 2);
    float m  = fmaxf(ml0.x, ml1.x);
    float a0 = exp2v(ml0.x - m);
    float a1 = exp2v(ml1.x - m);
    float inv = 1.0f / (a0 * ml0.y + a1 * ml1.y);
    a0 *= inv; a1 *= inv;
    float4 o0 = *reinterpret_cast<const float4*>(wsO + (size_t)R * DDIM + d4);
    float4 o1 = *reinterpret_cast<const float4*>(wsO + ((size_t)NR + R) * DDIM + d4);
    float4 o = {a0 * o0.x + a1 * o1.x, a0 * o0.y + a1 * o1.y,
                a0 * o0.z + a1 * o1.z, a0 * o0.w + a1 * o1.w};
    *reinterpret_cast<float4*>(Og + (size_t)R * DDIM + d4) = o;
}

extern "C" void kernel_launch(void* const* d_in, const int* in_sizes, int n_in,
                              void* d_out, int out_size, void* d_ws, size_t ws_size,
                              hipStream_t stream) {
    const float* Q = (const float*)d_in[0];
    const float* K = (const float*)d_in[1];
    const float* V = (const float*)d_in[2];
    float* O = (float*)d_out;

    const size_t nO  = (size_t)2 * NHEAD * S_LEN * DDIM;   // partial O floats
    const size_t nML = (size_t)2 * NHEAD * S_LEN * 2;      // (m,l) floats
    const size_t need = (nO + nML) * sizeof(float);

    if (ws_size >= need) {
        float* wsO  = (float*)d_ws;
        float* wsML = wsO + nO;
        dim3 grid(S_LEN / QBLK, NHEAD, 2);
        attn_fwd<2><<<grid, dim3(256, 1, 1), 0, stream>>>(Q, K, V, O, wsO, wsML);
        int nthr = NHEAD * S_LEN * (DDIM / 4);
        combine2<<<dim3(nthr / 256), dim3(256, 1, 1), 0, stream>>>(wsO, wsML, O);
    } else {
        dim3 grid(S_LEN / QBLK, NHEAD, 1);
        attn_fwd<1><<<grid, dim3(256, 1, 1), 0, stream>>>(Q, K, V, O, nullptr, nullptr);
    }
}